// Round 1
// baseline (257.362 us; speedup 1.0000x reference)
//
#include <hip/hip_runtime.h>
#include <stdint.h>

typedef short short8 __attribute__((ext_vector_type(8)));
typedef float f32x4 __attribute__((ext_vector_type(4)));

#define N_TOT 32768
#define EV 4096

__device__ __forceinline__ unsigned short f2bf(float f){
  unsigned int x = __float_as_uint(f);
  x += 0x7FFFu + ((x >> 16) & 1u);
  return (unsigned short)(x >> 16);
}

// ---------------- Kernel A: s (fp32), h (bf16), U[:,0:256] = bf16(x) ----------------
__global__ __launch_bounds__(256, 2) void kA(
    const float* __restrict__ x, const float* __restrict__ Ws,
    const float* __restrict__ bs, const float* __restrict__ Wh,
    const float* __restrict__ bh, float* __restrict__ sOut,
    unsigned short* __restrict__ hOut, unsigned short* __restrict__ U)
{
  __shared__ float xs[64*256];   // 64 rows, float4-chunk XOR swizzle: chunk c4 of row r at (c4 ^ (r&7))
  const int t = threadIdx.x;
  const int r0 = blockIdx.x * 64;
  const float4* xg = (const float4*)(x + (size_t)r0*256);
  #pragma unroll
  for (int i=0;i<16;++i){
    int f = t + 256*i;
    int row = f >> 6, c4 = f & 63;
    float4 v = xg[f];
    *(float4*)&xs[row*256 + (c4 ^ (row&7))*4] = v;
    ushort4 ub = { f2bf(v.x), f2bf(v.y), f2bf(v.z), f2bf(v.w) };
    *(ushort4*)&U[(size_t)(r0+row)*320 + c4*4] = ub;
  }
  __syncthreads();
  // s: fp32. thread: row = t>>2, k-quarter = t&3 ; reduce across k-quarters via shfl.
  {
    int row = t >> 2, kq = t & 3;
    float a0=0.f,a1=0.f,a2=0.f,a3=0.f;
    const float4* wsr = (const float4*)Ws;   // Ws[k][0..3]
    #pragma unroll 4
    for (int i=0;i<16;++i){
      int c4 = kq*16 + i;
      float4 xv = *(const float4*)&xs[row*256 + (c4 ^ (row&7))*4];
      float4 w0 = wsr[c4*4+0], w1 = wsr[c4*4+1], w2 = wsr[c4*4+2], w3 = wsr[c4*4+3];
      a0 += xv.x*w0.x + xv.y*w1.x + xv.z*w2.x + xv.w*w3.x;
      a1 += xv.x*w0.y + xv.y*w1.y + xv.z*w2.y + xv.w*w3.y;
      a2 += xv.x*w0.z + xv.y*w1.z + xv.z*w2.z + xv.w*w3.z;
      a3 += xv.x*w0.w + xv.y*w1.w + xv.z*w2.w + xv.w*w3.w;
    }
    a0 += __shfl_xor(a0,1); a0 += __shfl_xor(a0,2);
    a1 += __shfl_xor(a1,1); a1 += __shfl_xor(a1,2);
    a2 += __shfl_xor(a2,1); a2 += __shfl_xor(a2,2);
    a3 += __shfl_xor(a3,1); a3 += __shfl_xor(a3,2);
    if (kq == 0){
      float4 sv = { a0+bs[0], a1+bs[1], a2+bs[2], a3+bs[3] };
      ((float4*)sOut)[r0 + row] = sv;
    }
  }
  // h: row = t&63, col-group (4 cols) = wave + 4*rd  -> wave-uniform W addressing
  const float4* whr = (const float4*)Wh;   // Wh[k][32] = 8 float4 per k
  #pragma unroll
  for (int rd=0; rd<2; ++rd){
    int row = t & 63;
    int cg = (t >> 6) + rd*4;
    int cgu = __builtin_amdgcn_readfirstlane(cg);
    float a0=0.f,a1=0.f,a2=0.f,a3=0.f;
    #pragma unroll 4
    for (int c4=0;c4<64;++c4){
      float4 xv = *(const float4*)&xs[row*256 + (c4 ^ (row&7))*4];
      float4 w0 = whr[(c4*4+0)*8 + cgu];
      float4 w1 = whr[(c4*4+1)*8 + cgu];
      float4 w2 = whr[(c4*4+2)*8 + cgu];
      float4 w3 = whr[(c4*4+3)*8 + cgu];
      a0 += xv.x*w0.x + xv.y*w1.x + xv.z*w2.x + xv.w*w3.x;
      a1 += xv.x*w0.y + xv.y*w1.y + xv.z*w2.y + xv.w*w3.y;
      a2 += xv.x*w0.z + xv.y*w1.z + xv.z*w2.z + xv.w*w3.z;
      a3 += xv.x*w0.w + xv.y*w1.w + xv.z*w2.w + xv.w*w3.w;
    }
    float4 bv = ((const float4*)bh)[cgu];
    ushort4 hb = { f2bf(a0+bv.x), f2bf(a1+bv.y), f2bf(a2+bv.z), f2bf(a3+bv.w) };
    *(ushort4*)&hOut[(size_t)(r0+row)*32 + cgu*4] = hb;
  }
}

// ---------------- Kernel B: exact kNN(16) + weighted mean/max aggregation -> U[:,256:320] ----
// block = 256 thr = 64 queries; 4 lanes/query, lane-quarter q handles j = 4*i + q.
// candidates packed (d2bits & 0xFFFFF000) | j  (12-bit j, ties break toward smaller j like top_k)
#define BUBBLE16(v)                                              \
  { _Pragma("unroll")                                            \
    for (int k=0;k<16;++k){                                      \
      unsigned int mn = (v) < bp[k] ? (v) : bp[k];               \
      unsigned int mx = (v) < bp[k] ? bp[k] : (v);               \
      bp[k] = mn; (v) = mx;                                      \
    }                                                            \
    kth = bp[15]; }

__global__ __launch_bounds__(256, 2) void kB(
    const float* __restrict__ sIn, const unsigned short* __restrict__ hIn,
    unsigned short* __restrict__ U)
{
  __shared__ float4 sE[1024];            // 16KB chunk of this event's s
  __shared__ unsigned int cbuf[256*8];   // per-thread candidate ring (8 slots)
  const int t = threadIdx.x;
  const int e = blockIdx.x >> 6;
  const int qblk = (blockIdx.x & 63) * 64;
  const int l = t & 63, wv = t >> 6;
  const int q = l >> 4, lq = l & 15;
  const int qloc = qblk + wv*16 + lq;    // event-local query row
  const float4* sg = (const float4*)sIn;
  const float4 si = sg[(size_t)e*EV + qloc];
  unsigned int bp[16];
  #pragma unroll
  for (int k=0;k<16;++k) bp[k] = 0xFFFFFFFFu;
  unsigned int kth = 0xFFFFFFFFu;
  int cnt = 0;
  const int cb = t*8;

  for (int ch=0; ch<4; ++ch){
    __syncthreads();
    #pragma unroll
    for (int i=0;i<4;++i) sE[t + 256*i] = sg[(size_t)e*EV + ch*1024 + t + 256*i];
    __syncthreads();
    for (int ii=0; ii<256; ii+=4){
      #pragma unroll
      for (int u=0; u<4; ++u){
        int iloc = (ii+u)*4 + q;                 // quarter-staggered -> conflict-free broadcast
        float4 sj = sE[iloc];
        int j = ch*1024 + iloc;
        float dx = sj.x-si.x, dy = sj.y-si.y, dz = sj.z-si.z, dw = sj.w-si.w;
        float d2 = dx*dx + dy*dy + dz*dz + dw*dw;
        unsigned int key = (__float_as_uint(d2) & 0xFFFFF000u) | (unsigned int)j;
        if (key < kth){ cbuf[cb + cnt] = key; cnt++; }
      }
      if (__any(cnt >= 4)){                       // batched drain (cap 8, add<=4/batch)
        for (;;){
          if (!__any(cnt > 0)) break;
          unsigned int v = 0xFFFFFFFFu;
          if (cnt > 0){ cnt--; v = cbuf[cb + cnt]; }
          if (v < kth){ BUBBLE16(v) }
        }
      }
    }
  }
  for (;;){                                       // final drain
    if (!__any(cnt > 0)) break;
    unsigned int v = 0xFFFFFFFFu;
    if (cnt > 0){ cnt--; v = cbuf[cb + cnt]; }
    if (v < kth){ BUBBLE16(v) }
  }

  // in-wave merge across the 4 quarter-lanes of each query (xor 16, then xor 32)
  #pragma unroll
  for (int st=0; st<2; ++st){
    const int msk = (st==0) ? 16 : 32;
    unsigned int ot[16], c[16];
    #pragma unroll
    for (int k=0;k<16;++k) ot[k] = (unsigned int)__shfl_xor((int)bp[k], msk, 64);
    #pragma unroll
    for (int k=0;k<16;++k){ unsigned int b2 = ot[15-k]; c[k] = bp[k] < b2 ? bp[k] : b2; }
    #pragma unroll
    for (int d=8; d>=1; d>>=1){
      #pragma unroll
      for (int i=0;i<16;++i){
        if ((i & d) == 0){
          unsigned int lo = c[i] < c[i+d] ? c[i] : c[i+d];
          unsigned int hi = c[i] < c[i+d] ? c[i+d] : c[i];
          c[i] = lo; c[i+d] = hi;
        }
      }
    }
    #pragma unroll
    for (int k=0;k<16;++k) bp[k] = c[k];
  }

  // gather + aggregate: each quarter-lane handles 4 of the 16 neighbors
  unsigned int mk[4];
  #pragma unroll
  for (int i=0;i<4;++i){
    unsigned int v = bp[i];
    v = (q==1) ? bp[4+i]  : v;
    v = (q==2) ? bp[8+i]  : v;
    v = (q==3) ? bp[12+i] : v;
    mk[i] = v;
  }
  float am[32], ax[32];
  #pragma unroll
  for (int p=0;p<32;++p){ am[p]=0.f; ax[p]=-3.4e38f; }
  const uint4* hb = (const uint4*)(hIn + (size_t)e*EV*32);
  #pragma unroll
  for (int i=0;i<4;++i){
    unsigned int key = mk[i];
    int j = (int)(key & 0xFFFu);
    float d2 = __uint_as_float(key & 0xFFFFF000u);
    float w = __expf(-10.f * d2);
    #pragma unroll
    for (int f=0; f<4; ++f){
      uint4 hv = hb[j*4 + f];
      unsigned int uu[4] = {hv.x, hv.y, hv.z, hv.w};
      #pragma unroll
      for (int c2=0;c2<4;++c2){
        float flo = __uint_as_float(uu[c2] << 16);
        float fhi = __uint_as_float(uu[c2] & 0xFFFF0000u);
        int p = f*8 + c2*2;
        float m0 = w*flo, m1 = w*fhi;
        am[p]   += m0;               am[p+1] += m1;
        ax[p]    = fmaxf(ax[p], m0); ax[p+1]  = fmaxf(ax[p+1], m1);
      }
    }
  }
  #pragma unroll
  for (int p=0;p<32;++p){
    am[p] += __shfl_xor(am[p], 16, 64);
    am[p] += __shfl_xor(am[p], 32, 64);
    float o = __shfl_xor(ax[p], 16, 64); ax[p] = fmaxf(ax[p], o);
    o = __shfl_xor(ax[p], 32, 64);       ax[p] = fmaxf(ax[p], o);
  }
  if (q == 0){
    unsigned short* Ur = U + ((size_t)e*EV + qloc)*320;
    #pragma unroll
    for (int g8=0; g8<4; ++g8){
      uint4 pm, px;
      pm.x = (unsigned int)f2bf(am[g8*8+0]*(1.f/16.f)) | ((unsigned int)f2bf(am[g8*8+1]*(1.f/16.f))<<16);
      pm.y = (unsigned int)f2bf(am[g8*8+2]*(1.f/16.f)) | ((unsigned int)f2bf(am[g8*8+3]*(1.f/16.f))<<16);
      pm.z = (unsigned int)f2bf(am[g8*8+4]*(1.f/16.f)) | ((unsigned int)f2bf(am[g8*8+5]*(1.f/16.f))<<16);
      pm.w = (unsigned int)f2bf(am[g8*8+6]*(1.f/16.f)) | ((unsigned int)f2bf(am[g8*8+7]*(1.f/16.f))<<16);
      px.x = (unsigned int)f2bf(ax[g8*8+0]) | ((unsigned int)f2bf(ax[g8*8+1])<<16);
      px.y = (unsigned int)f2bf(ax[g8*8+2]) | ((unsigned int)f2bf(ax[g8*8+3])<<16);
      px.z = (unsigned int)f2bf(ax[g8*8+4]) | ((unsigned int)f2bf(ax[g8*8+5])<<16);
      px.w = (unsigned int)f2bf(ax[g8*8+6]) | ((unsigned int)f2bf(ax[g8*8+7])<<16);
      *(uint4*)(Ur + 256 + g8*8) = pm;
      *(uint4*)(Ur + 288 + g8*8) = px;
    }
  }
}

// ---------------- Kernel C: x_new = U @ Wo + bo ; y = x + x_new ; LayerNorm -> out ----------------
__global__ __launch_bounds__(256, 2) void kC(
    const unsigned short* __restrict__ U, const float* __restrict__ Wo,
    const float* __restrict__ bo, const float* __restrict__ x,
    const float* __restrict__ gamma, const float* __restrict__ beta,
    float* __restrict__ out)
{
  __shared__ unsigned short At[64*40];    // [64 rows][32k padded to 40]
  __shared__ unsigned short Bt[256*40];   // [256 cols][32k padded to 40]
  __shared__ float ps[64*4], pq[64*4];
  const int t = threadIdx.x;
  const int r0 = blockIdx.x * 64;
  const int l = t & 63, wv = t >> 6;
  const int lq = l & 15, g = l >> 4;
  f32x4 acc[4][4];
  const f32x4 zero = {0.f,0.f,0.f,0.f};
  #pragma unroll
  for (int m=0;m<4;++m)
    #pragma unroll
    for (int n=0;n<4;++n) acc[m][n] = zero;

  for (int kk=0; kk<10; ++kk){
    const int k0 = kk*32;
    __syncthreads();
    { // stage A (bf16 copy from U)
      int row = t >> 2, ko = (t & 3)*8;
      uint4 av = *(const uint4*)(U + (size_t)(r0+row)*320 + k0 + ko);
      *(uint4*)(At + row*40 + ko) = av;
    }
    { // stage B^T (Wo fp32 -> bf16)
      int col = t;
      #pragma unroll
      for (int k8=0;k8<4;++k8){
        float v0 = Wo[(size_t)(k0+k8*8+0)*256 + col];
        float v1 = Wo[(size_t)(k0+k8*8+1)*256 + col];
        float v2 = Wo[(size_t)(k0+k8*8+2)*256 + col];
        float v3 = Wo[(size_t)(k0+k8*8+3)*256 + col];
        float v4 = Wo[(size_t)(k0+k8*8+4)*256 + col];
        float v5 = Wo[(size_t)(k0+k8*8+5)*256 + col];
        float v6 = Wo[(size_t)(k0+k8*8+6)*256 + col];
        float v7 = Wo[(size_t)(k0+k8*8+7)*256 + col];
        uint4 w4;
        w4.x = (unsigned int)f2bf(v0) | ((unsigned int)f2bf(v1)<<16);
        w4.y = (unsigned int)f2bf(v2) | ((unsigned int)f2bf(v3)<<16);
        w4.z = (unsigned int)f2bf(v4) | ((unsigned int)f2bf(v5)<<16);
        w4.w = (unsigned int)f2bf(v6) | ((unsigned int)f2bf(v7)<<16);
        *(uint4*)(Bt + col*40 + k8*8) = w4;
      }
    }
    __syncthreads();
    short8 a[4], b[4];
    #pragma unroll
    for (int m=0;m<4;++m) a[m] = *(const short8*)(At + (16*m+lq)*40 + g*8);
    #pragma unroll
    for (int n=0;n<4;++n) b[n] = *(const short8*)(Bt + (wv*64 + 16*n + lq)*40 + g*8);
    #pragma unroll
    for (int m=0;m<4;++m)
      #pragma unroll
      for (int n=0;n<4;++n)
        acc[m][n] = __builtin_amdgcn_mfma_f32_16x16x32_bf16(a[m], b[n], acc[m][n], 0, 0, 0);
  }

  // epilogue: + bo + x(residual), LayerNorm over 256 cols
  float bo_n[4], ga_n[4], be_n[4];
  #pragma unroll
  for (int n=0;n<4;++n){
    int colg = wv*64 + 16*n + lq;
    bo_n[n] = bo[colg]; ga_n[n] = gamma[colg]; be_n[n] = beta[colg];
  }
  float pr[4][4], pr2[4][4];
  #pragma unroll
  for (int m=0;m<4;++m){
    #pragma unroll
    for (int rg=0;rg<4;++rg){
      int rowg = r0 + 16*m + g*4 + rg;
      float sum=0.f, sq=0.f;
      #pragma unroll
      for (int n=0;n<4;++n){
        int colg = wv*64 + 16*n + lq;
        float y = acc[m][n][rg] + bo_n[n] + x[(size_t)rowg*256 + colg];
        acc[m][n][rg] = y;
        sum += y; sq += y*y;
      }
      sum += __shfl_xor(sum,1); sq += __shfl_xor(sq,1);
      sum += __shfl_xor(sum,2); sq += __shfl_xor(sq,2);
      sum += __shfl_xor(sum,4); sq += __shfl_xor(sq,4);
      sum += __shfl_xor(sum,8); sq += __shfl_xor(sq,8);
      pr[m][rg]=sum; pr2[m][rg]=sq;
    }
  }
  if (lq == 0){
    #pragma unroll
    for (int m=0;m<4;++m)
      #pragma unroll
      for (int rg=0;rg<4;++rg){
        int rowl = 16*m + g*4 + rg;
        ps[rowl*4 + wv] = pr[m][rg];
        pq[rowl*4 + wv] = pr2[m][rg];
      }
  }
  __syncthreads();
  #pragma unroll
  for (int m=0;m<4;++m){
    #pragma unroll
    for (int rg=0;rg<4;++rg){
      int rowl = 16*m + g*4 + rg;
      float sum = ps[rowl*4+0]+ps[rowl*4+1]+ps[rowl*4+2]+ps[rowl*4+3];
      float sq  = pq[rowl*4+0]+pq[rowl*4+1]+pq[rowl*4+2]+pq[rowl*4+3];
      float mu  = sum * (1.f/256.f);
      float var = sq * (1.f/256.f) - mu*mu;
      float inv = rsqrtf(var + 1e-5f);
      int rowg = r0 + rowl;
      #pragma unroll
      for (int n=0;n<4;++n){
        int colg = wv*64 + 16*n + lq;
        out[(size_t)rowg*256 + colg] = ga_n[n]*(acc[m][n][rg] - mu)*inv + be_n[n];
      }
    }
  }
}

extern "C" void kernel_launch(void* const* d_in, const int* in_sizes, int n_in,
                              void* d_out, int out_size, void* d_ws, size_t ws_size,
                              hipStream_t stream)
{
  const float* x     = (const float*)d_in[0];
  // d_in[1] = batch_index (block-sorted equal events; unused)
  const float* Ws    = (const float*)d_in[2];
  const float* bs    = (const float*)d_in[3];
  const float* Wh    = (const float*)d_in[4];
  const float* bh    = (const float*)d_in[5];
  const float* Wo    = (const float*)d_in[6];
  const float* bo    = (const float*)d_in[7];
  const float* gamma = (const float*)d_in[8];
  const float* beta  = (const float*)d_in[9];
  float* out = (float*)d_out;

  char* ws = (char*)d_ws;
  float*          sBuf = (float*)ws;                               // N*4 f32   = 0.5 MB
  unsigned short* hBuf = (unsigned short*)(ws + 524288);           // N*32 bf16 = 2 MB
  unsigned short* U    = (unsigned short*)(ws + 524288 + 2097152); // N*320 bf16 = 21 MB

  kA<<<dim3(N_TOT/64), dim3(256), 0, stream>>>(x, Ws, bs, Wh, bh, sBuf, hBuf, U);
  kB<<<dim3(N_TOT/64), dim3(256), 0, stream>>>(sBuf, hBuf, U);
  kC<<<dim3(N_TOT/64), dim3(256), 0, stream>>>(U, Wo, bo, x, gamma, beta, out);
}